// Round 6
// baseline (673.753 us; speedup 1.0000x reference)
//
#include <hip/hip_runtime.h>

typedef int iv4 __attribute__((ext_vector_type(4)));

// =================== v6: two-pass region-bucketed gather ===================
#define G2     256      // blocks (1 per CU) for both passes
#define BLK2   1024     // threads per block (16 waves)
#define NW     16       // waves per block
#define NREGS  128      // x regions (256 KB each at n_x = 2^23)
#define RSH    16       // region shift: ptr >> 16
#define CAP    32512    // LDS segment-accumulator capacity (floats)

// ---- Pass 1: bucket each block's edge range by ptr-region into ws ----
__global__ __launch_bounds__(BLK2) void bucket_kernel(
    const float* __restrict__ x,
    const int*   __restrict__ ptrs,
    const int*   __restrict__ csr,
    float*       __restrict__ out,
    unsigned*    __restrict__ wse,   // [n_edges] packed entries
    int*         __restrict__ wso,   // [G2 * (NREGS+1)] region bounds per block
    int eb)                          // edges per block
{
    __shared__ int whist[NW][NREGS];     // per-wave region histograms
    __shared__ int wcur[NW][NREGS];      // per-wave scatter cursors
    __shared__ int bounds[NREGS + 1];    // block-level region prefix

    const int c = blockIdx.x, tid = threadIdx.x, w = tid >> 6;
    const long long base = (long long)c * eb;
    const int seg_base = csr[base];
    const iv4* p4 = reinterpret_cast<const iv4*>(ptrs + base);
    const iv4* s4 = reinterpret_cast<const iv4*>(csr + base);
    const int iters = eb >> 12;          // eb / (BLK2*4)

    for (int i = tid; i < NW * NREGS; i += BLK2) (&whist[0][0])[i] = 0;
    __syncthreads();

    // Phase A: wave-private histogram (LDS atomics, wave-local -> low depth)
    for (int it = 0; it < iters; ++it) {
        iv4 p = __builtin_nontemporal_load(p4 + (size_t)it * BLK2 + tid);
        atomicAdd(&whist[w][p[0] >> RSH], 1);
        atomicAdd(&whist[w][p[1] >> RSH], 1);
        atomicAdd(&whist[w][p[2] >> RSH], 1);
        atomicAdd(&whist[w][p[3] >> RSH], 1);
    }
    __syncthreads();

    // Block-level region prefix
    if (tid < NREGS) {
        int s = 0;
        #pragma unroll
        for (int ww = 0; ww < NW; ++ww) s += whist[ww][tid];
        bounds[tid] = s;
    }
    __syncthreads();
    if (tid == 0) {
        int acc = 0;
        for (int r = 0; r < NREGS; ++r) { int t = bounds[r]; bounds[r] = acc; acc += t; }
        bounds[NREGS] = acc;             // == eb
    }
    __syncthreads();
    // Exact per-(wave, region) bases
    for (int idx = tid; idx < NW * NREGS; idx += BLK2) {
        int ww = idx >> 7, r = idx & (NREGS - 1);
        int b = bounds[r];
        for (int w2 = 0; w2 < ww; ++w2) b += whist[w2][r];
        wcur[ww][r] = b;
    }
    for (int i = tid; i <= NREGS; i += BLK2) wso[c * (NREGS + 1) + i] = bounds[i];
    __syncthreads();

    // Phase B: scatter packed entries (unstable ranking is fine -- the
    // consumer accumulates order-independently via LDS atomics)
    for (int it = 0; it < iters; ++it) {
        iv4 p = __builtin_nontemporal_load(p4 + (size_t)it * BLK2 + tid);
        iv4 s = __builtin_nontemporal_load(s4 + (size_t)it * BLK2 + tid);
        #pragma unroll
        for (int k = 0; k < 4; ++k) {
            int pp = p[k], ss = s[k];
            int r  = pp >> RSH;
            int sl = ss - seg_base;
            unsigned pk;
            if (sl >= 0xFFFF) {           // pathological seg range: direct add
                atomicAdd(out + ss, x[pp]);
                pk = (((unsigned)pp & 0xFFFFu) << 16) | 0xFFFFu;  // NOP sentinel
            } else {
                pk = (((unsigned)pp & 0xFFFFu) << 16) | (unsigned)sl;
            }
            int pos = atomicAdd(&wcur[w][r], 1);
            wse[base + pos] = pk;
        }
    }
}

// ---- Pass 2: global region sweep; gather + LDS segment accumulate ----
__global__ __launch_bounds__(BLK2) void consume_kernel(
    const float*    __restrict__ x,
    const int*      __restrict__ csr,
    float*          __restrict__ out,
    const unsigned* __restrict__ wse,
    const int*      __restrict__ wso,
    int eb)
{
    __shared__ float accum[CAP];         // 127 KB segment accumulator
    __shared__ int   boundsl[NREGS + 1];

    const int c = blockIdx.x, tid = threadIdx.x;
    const long long base = (long long)c * eb;
    for (int i = tid; i < CAP; i += BLK2) accum[i] = 0.f;
    for (int i = tid; i <= NREGS; i += BLK2) boundsl[i] = wso[c * (NREGS + 1) + i];
    const int seg_base = csr[base];
    const int seg_last = csr[base + eb - 1];
    __syncthreads();

    // Region-major sweep: all 256 blocks dwell on ~the same 256 KB region of x
    // at ~the same time -> lambda = 8 accesses/line -> ~87% L2 hits.
    for (int r = 0; r < NREGS; ++r) {
        const int lo = boundsl[r], hi = boundsl[r + 1];
        const int rbase = r << RSH;
        for (int i = lo + tid; i < hi; i += BLK2) {
            unsigned pk = __builtin_nontemporal_load(wse + base + i);
            int   sl  = (int)(pk & 0xFFFFu);
            float val = x[rbase | (int)(pk >> 16)];
            if (sl == 0xFFFF) continue;              // handled in pass 1
            if (sl < CAP) atomicAdd(&accum[sl], val);
            else          atomicAdd(out + seg_base + sl, val);  // rare overflow
        }
    }
    __syncthreads();

    // Flush: interior segments exclusive (csr sorted) -> plain coalesced
    // stores; the two chunk-boundary segments may be shared -> atomicAdd.
    const int range = seg_last - seg_base + 1;
    const int hi = range < CAP ? range : CAP;
    for (int i = tid; i < hi; i += BLK2) {
        float v = accum[i];
        if (i == 0 || i == range - 1) {
            if (v != 0.f) atomicAdd(out + seg_base + i, v);
        } else {
            out[seg_base + i] = v;
        }
    }
}

// =================== round-5 fallback (generic sizes) ===================
#define EPT   16
#define BLK   256
#define CHUNK (BLK * EPT)
#define NREG  16
#define SW(s) ((s) ^ (((s) >> 4) & 0xF))

__global__ __launch_bounds__(BLK, 4) void seg_gather_sort_kernel(
    const float* __restrict__ x,
    const int*   __restrict__ ptrs,
    const int*   __restrict__ csr,
    float*       __restrict__ out,
    int n_edges, int rshift, int n_chunks)
{
    __shared__ int      hist[NREG];
    __shared__ int      bounds[NREG + 1];
    __shared__ unsigned packed[CHUNK];
    __shared__ float    vlds[CHUNK];

    const int tid = threadIdx.x;
    const unsigned lmask = (1u << rshift) - 1u;

    for (int c = blockIdx.x; c < n_chunks; c += gridDim.x) {
        const long long base_e = (long long)c * CHUNK;

        if (base_e + CHUNK <= n_edges) {
            const long long e0 = base_e + (long long)tid * EPT;
            const iv4* p4 = reinterpret_cast<const iv4*>(ptrs + e0);
            const iv4* c4 = reinterpret_cast<const iv4*>(csr + e0);
            int ps[EPT], cs[EPT];
            #pragma unroll
            for (int q = 0; q < EPT / 4; ++q) {
                iv4 p = __builtin_nontemporal_load(p4 + q);
                ps[q*4+0] = p[0]; ps[q*4+1] = p[1]; ps[q*4+2] = p[2]; ps[q*4+3] = p[3];
            }
            #pragma unroll
            for (int q = 0; q < EPT / 4; ++q) {
                iv4 cc = __builtin_nontemporal_load(c4 + q);
                cs[q*4+0] = cc[0]; cs[q*4+1] = cc[1]; cs[q*4+2] = cc[2]; cs[q*4+3] = cc[3];
            }
            if (tid < NREG) hist[tid] = 0;
            __syncthreads();
            #pragma unroll
            for (int i = 0; i < EPT; ++i) atomicAdd(&hist[ps[i] >> rshift], 1);
            __syncthreads();
            if (tid == 0) {
                int acc = 0; bounds[0] = 0;
                #pragma unroll
                for (int r = 0; r < NREG; ++r) { acc += hist[r]; bounds[r+1] = acc; }
                #pragma unroll
                for (int r = 0; r < NREG; ++r) hist[r] = bounds[r];
            }
            __syncthreads();
            #pragma unroll
            for (int i = 0; i < EPT; ++i) {
                int r   = ps[i] >> rshift;
                int pos = atomicAdd(&hist[r], 1);
                packed[pos] = (((unsigned)ps[i] & lmask) << 12) | (unsigned)(tid*EPT+i);
            }
            __syncthreads();
            {
                int r = 0;
                #pragma unroll
                for (int k = 0; k < EPT; ++k) {
                    int e = k * BLK + tid;
                    while (e >= bounds[r + 1]) ++r;
                    unsigned pk = packed[e];
                    int ptr  = (r << rshift) | (int)(pk >> 12);
                    int slot = (int)(pk & 0xFFFu);
                    vlds[SW(slot)] = x[ptr];
                }
            }
            __syncthreads();
            float v[EPT];
            #pragma unroll
            for (int i = 0; i < EPT; ++i) v[i] = vlds[SW(tid * EPT + i)];
            int   cur   = cs[0];
            float sum   = 0.f;
            bool  first = true;
            #pragma unroll
            for (int i = 0; i < EPT; ++i) {
                int seg = cs[i];
                if (seg != cur) {
                    if (first) { atomicAdd(out + cur, sum); first = false; }
                    else       { out[cur] = sum; }
                    cur = seg; sum = 0.f;
                }
                sum += v[i];
            }
            atomicAdd(out + cur, sum);
            __syncthreads();
        } else {
            long long e0 = base_e + (long long)tid * EPT;
            if (e0 < n_edges) {
                long long eend = e0 + EPT; if (eend > n_edges) eend = n_edges;
                int cur = csr[e0]; float sum = 0.f; bool first = true;
                for (long long e = e0; e < eend; ++e) {
                    int seg = csr[e];
                    if (seg != cur) {
                        if (first) { atomicAdd(out + cur, sum); first = false; }
                        else       { out[cur] = sum; }
                        cur = seg; sum = 0.f;
                    }
                    sum += x[ptrs[e]];
                }
                atomicAdd(out + cur, sum);
            }
        }
    }
}

extern "C" void kernel_launch(void* const* d_in, const int* in_sizes, int n_in,
                              void* d_out, int out_size, void* d_ws, size_t ws_size,
                              hipStream_t stream) {
    const float* x    = (const float*)d_in[0];
    const int*   ptrs = (const int*)d_in[1];
    const int*   csr  = (const int*)d_in[2];
    float*       out  = (float*)d_out;

    const int n_x     = in_sizes[0];
    const int n_edges = in_sizes[2];

    // Zero base for atomics + empty segments (d_out poisoned by harness).
    (void)hipMemsetAsync(out, 0, (size_t)out_size * sizeof(float), stream);

    const size_t ws_need = (size_t)n_edges * 4 + (size_t)G2 * (NREGS + 1) * 4;
    const bool v6_ok = (n_edges % (G2 * BLK2 * 4) == 0) &&
                       (n_x <= (NREGS << RSH)) &&
                       (ws_size >= ws_need);

    if (v6_ok) {
        const int eb = n_edges / G2;                 // 131072
        unsigned* wse = (unsigned*)d_ws;
        int*      wso = (int*)d_ws + n_edges;
        bucket_kernel <<<G2, BLK2, 0, stream>>>(x, ptrs, csr, out, wse, wso, eb);
        consume_kernel<<<G2, BLK2, 0, stream>>>(x, csr, out, wse, wso, eb);
    } else {
        int rshift = 0;
        while ((1LL << rshift) < (n_x + NREG - 1) / NREG) ++rshift;
        const int n_chunks = (int)(((long long)n_edges + CHUNK - 1) / CHUNK);
        int grid = 1024; if (grid > n_chunks) grid = n_chunks;
        seg_gather_sort_kernel<<<grid, BLK, 0, stream>>>(
            x, ptrs, csr, out, n_edges, rshift, n_chunks);
    }
}

// Round 7
// 315.214 us; speedup vs baseline: 2.1374x; 2.1374x over previous
//
#include <hip/hip_runtime.h>

typedef int      iv4 __attribute__((ext_vector_type(4)));
typedef unsigned uv4 __attribute__((ext_vector_type(4)));

// ============ v7: chunk-local LDS sort (coalesced write) + region sweep ======
#define NREGS   128               // x regions, 256 KB each at n_x = 2^23
#define RSH     16                // region shift: ptr >> 16
#define BLK1    512
#define EPT1    16
#define CHUNK1  (BLK1 * EPT1)     // 8192 edges per pass-1 chunk
#define CPB     16                // chunks per consume block (= waves in pass 2)
#define BLK2    1024
#define CAP     38400             // LDS segment-accumulator capacity (floats)

// ---- Pass 1: sort each 8192-edge chunk by region, write contiguously ----
__global__ __launch_bounds__(BLK1) void sort_chunks_kernel(
    const float* __restrict__ x,     // only for the (never-taken) sentinel path
    const int*   __restrict__ ptrs,
    const int*   __restrict__ csr,
    float*       __restrict__ out,
    unsigned*    __restrict__ wse,   // [n_edges] packed entries, chunk-contiguous
    int*         __restrict__ wsb,   // [n_chunks * (NREGS+1)] per-chunk bounds
    long long eb)                    // edges per consume block = CPB*CHUNK1
{
    __shared__ int      hist[NREGS];      // counts -> scatter cursors
    __shared__ int      bounds[NREGS + 1];
    __shared__ unsigned packed[CHUNK1];   // 32 KB

    const int c = blockIdx.x, tid = threadIdx.x;
    const long long base = (long long)c * CHUNK1;
    const int cb = (int)(base / eb);                  // owning consume block
    const int seg_base = csr[(long long)cb * eb];

    if (tid < NREGS) hist[tid] = 0;
    __syncthreads();

    // coalesced index loads into registers (wave reads 1 KB lines)
    int ps[EPT1], cs[EPT1];
    const iv4* p4 = reinterpret_cast<const iv4*>(ptrs + base);
    const iv4* s4 = reinterpret_cast<const iv4*>(csr + base);
    #pragma unroll
    for (int q = 0; q < EPT1 / 4; ++q) {
        iv4 p = __builtin_nontemporal_load(p4 + q * BLK1 + tid);
        ps[q*4+0] = p[0]; ps[q*4+1] = p[1]; ps[q*4+2] = p[2]; ps[q*4+3] = p[3];
    }
    #pragma unroll
    for (int q = 0; q < EPT1 / 4; ++q) {
        iv4 s = __builtin_nontemporal_load(s4 + q * BLK1 + tid);
        cs[q*4+0] = s[0]; cs[q*4+1] = s[1]; cs[q*4+2] = s[2]; cs[q*4+3] = s[3];
    }

    // histogram
    #pragma unroll
    for (int i = 0; i < EPT1; ++i) atomicAdd(&hist[ps[i] >> RSH], 1);
    __syncthreads();
    if (tid == 0) {
        int acc = 0;
        #pragma unroll
        for (int r = 0; r < NREGS; ++r) { bounds[r] = acc; acc += hist[r]; }
        bounds[NREGS] = acc;                           // == CHUNK1
    }
    __syncthreads();
    if (tid < NREGS) hist[tid] = bounds[tid];          // cursors
    __syncthreads();

    // rank + scatter into LDS (unstable ranking is fine: consumer is
    // order-independent via LDS atomics)
    #pragma unroll
    for (int i = 0; i < EPT1; ++i) {
        int pp = ps[i], ss = cs[i];
        int r  = pp >> RSH;
        int sl = ss - seg_base;
        unsigned pk;
        if (sl >= 0xFFFF) {                            // pathological: direct add
            atomicAdd(out + ss, x[pp]);
            pk = (((unsigned)pp & 0xFFFFu) << 16) | 0xFFFFu;   // NOP sentinel
        } else {
            pk = (((unsigned)pp & 0xFFFFu) << 16) | (unsigned)sl;
        }
        int pos = atomicAdd(&hist[r], 1);
        packed[pos] = pk;
    }
    __syncthreads();

    // contiguous coalesced write-out of the sorted chunk (16 KB) + bounds
    {
        const uv4* pl = reinterpret_cast<const uv4*>(packed);
        uv4* w4 = reinterpret_cast<uv4*>(wse + base);
        for (int i = tid; i < CHUNK1 / 4; i += BLK1)
            __builtin_nontemporal_store(pl[i], w4 + i);
    }
    for (int i = tid; i <= NREGS; i += BLK1)
        wsb[(size_t)c * (NREGS + 1) + i] = bounds[i];
}

// ---- Pass 2: global region sweep; gather + LDS segment accumulate ----
__global__ __launch_bounds__(BLK2) void consume_kernel(
    const float*    __restrict__ x,
    const int*      __restrict__ csr,
    float*          __restrict__ out,
    const unsigned* __restrict__ wse,
    const int*      __restrict__ wsb,
    long long eb)
{
    __shared__ float accum[CAP];                 // 150 KB
    __shared__ int   cbnd[CPB][NREGS + 1];       // 8.1 KB

    const int c = blockIdx.x, tid = threadIdx.x;
    const int w = tid >> 6, lane = tid & 63;
    const long long base = (long long)c * eb;

    for (int i = tid; i < CAP; i += BLK2) accum[i] = 0.f;
    {
        const int* src = wsb + (size_t)c * CPB * (NREGS + 1);
        for (int i = tid; i < CPB * (NREGS + 1); i += BLK2)
            (&cbnd[0][0])[i] = src[i];
    }
    const int seg_base = csr[base];
    const int seg_last = csr[base + eb - 1];
    __syncthreads();

    // wave w owns chunk w (CPB == 16 waves). All 256 blocks dwell on the same
    // 256 KB region of x at ~the same time -> lambda = 8 -> ~87% L2 hits.
    const long long chunk_base = base + (long long)w * CHUNK1;
    for (int r = 0; r < NREGS; ++r) {
        const int lo = cbnd[w][r], hi = cbnd[w][r + 1];
        const int rb = r << RSH;
        for (int i = lo + lane; i < hi; i += 64) {
            unsigned pk = __builtin_nontemporal_load(wse + chunk_base + i);
            float val = x[rb | (int)(pk >> 16)];
            int   sl  = (int)(pk & 0xFFFFu);
            if (sl == 0xFFFF) continue;              // handled in pass 1
            if (sl < CAP) atomicAdd(&accum[sl], val);
            else          atomicAdd(out + seg_base + sl, val);   // rare overflow
        }
    }
    __syncthreads();

    // Flush: interior segments exclusive (csr sorted) -> plain coalesced
    // stores; the two block-boundary segments may be shared -> atomicAdd.
    const int range = seg_last - seg_base + 1;
    const int hi = range < CAP ? range : CAP;
    for (int i = tid; i < hi; i += BLK2) {
        float v = accum[i];
        if (i == 0 || i == range - 1) {
            if (v != 0.f) atomicAdd(out + seg_base + i, v);
        } else {
            out[seg_base + i] = v;
        }
    }
}

// =================== round-5 fallback (generic sizes) ===================
#define EPT   16
#define BLK   256
#define CHUNK (BLK * EPT)
#define NREG  16
#define SW(s) ((s) ^ (((s) >> 4) & 0xF))

__global__ __launch_bounds__(BLK, 4) void seg_gather_sort_kernel(
    const float* __restrict__ x,
    const int*   __restrict__ ptrs,
    const int*   __restrict__ csr,
    float*       __restrict__ out,
    int n_edges, int rshift, int n_chunks)
{
    __shared__ int      hist[NREG];
    __shared__ int      bounds[NREG + 1];
    __shared__ unsigned packed[CHUNK];
    __shared__ float    vlds[CHUNK];

    const int tid = threadIdx.x;
    const unsigned lmask = (1u << rshift) - 1u;

    for (int c = blockIdx.x; c < n_chunks; c += gridDim.x) {
        const long long base_e = (long long)c * CHUNK;
        if (base_e + CHUNK <= n_edges) {
            const long long e0 = base_e + (long long)tid * EPT;
            const iv4* p4 = reinterpret_cast<const iv4*>(ptrs + e0);
            const iv4* c4 = reinterpret_cast<const iv4*>(csr + e0);
            int ps[EPT], cs[EPT];
            #pragma unroll
            for (int q = 0; q < EPT / 4; ++q) {
                iv4 p = __builtin_nontemporal_load(p4 + q);
                ps[q*4+0] = p[0]; ps[q*4+1] = p[1]; ps[q*4+2] = p[2]; ps[q*4+3] = p[3];
            }
            #pragma unroll
            for (int q = 0; q < EPT / 4; ++q) {
                iv4 cc = __builtin_nontemporal_load(c4 + q);
                cs[q*4+0] = cc[0]; cs[q*4+1] = cc[1]; cs[q*4+2] = cc[2]; cs[q*4+3] = cc[3];
            }
            if (tid < NREG) hist[tid] = 0;
            __syncthreads();
            #pragma unroll
            for (int i = 0; i < EPT; ++i) atomicAdd(&hist[ps[i] >> rshift], 1);
            __syncthreads();
            if (tid == 0) {
                int acc = 0; bounds[0] = 0;
                #pragma unroll
                for (int r = 0; r < NREG; ++r) { acc += hist[r]; bounds[r+1] = acc; }
                #pragma unroll
                for (int r = 0; r < NREG; ++r) hist[r] = bounds[r];
            }
            __syncthreads();
            #pragma unroll
            for (int i = 0; i < EPT; ++i) {
                int r   = ps[i] >> rshift;
                int pos = atomicAdd(&hist[r], 1);
                packed[pos] = (((unsigned)ps[i] & lmask) << 12) | (unsigned)(tid*EPT+i);
            }
            __syncthreads();
            {
                int r = 0;
                #pragma unroll
                for (int k = 0; k < EPT; ++k) {
                    int e = k * BLK + tid;
                    while (e >= bounds[r + 1]) ++r;
                    unsigned pk = packed[e];
                    int ptr  = (r << rshift) | (int)(pk >> 12);
                    int slot = (int)(pk & 0xFFFu);
                    vlds[SW(slot)] = x[ptr];
                }
            }
            __syncthreads();
            float v[EPT];
            #pragma unroll
            for (int i = 0; i < EPT; ++i) v[i] = vlds[SW(tid * EPT + i)];
            int cur = cs[0]; float sum = 0.f; bool first = true;
            #pragma unroll
            for (int i = 0; i < EPT; ++i) {
                int seg = cs[i];
                if (seg != cur) {
                    if (first) { atomicAdd(out + cur, sum); first = false; }
                    else       { out[cur] = sum; }
                    cur = seg; sum = 0.f;
                }
                sum += v[i];
            }
            atomicAdd(out + cur, sum);
            __syncthreads();
        } else {
            long long e0 = base_e + (long long)tid * EPT;
            if (e0 < n_edges) {
                long long eend = e0 + EPT; if (eend > n_edges) eend = n_edges;
                int cur = csr[e0]; float sum = 0.f; bool first = true;
                for (long long e = e0; e < eend; ++e) {
                    int seg = csr[e];
                    if (seg != cur) {
                        if (first) { atomicAdd(out + cur, sum); first = false; }
                        else       { out[cur] = sum; }
                        cur = seg; sum = 0.f;
                    }
                    sum += x[ptrs[e]];
                }
                atomicAdd(out + cur, sum);
            }
        }
    }
}

extern "C" void kernel_launch(void* const* d_in, const int* in_sizes, int n_in,
                              void* d_out, int out_size, void* d_ws, size_t ws_size,
                              hipStream_t stream) {
    const float* x    = (const float*)d_in[0];
    const int*   ptrs = (const int*)d_in[1];
    const int*   csr  = (const int*)d_in[2];
    float*       out  = (float*)d_out;

    const int n_x     = in_sizes[0];
    const int n_edges = in_sizes[2];

    // Zero base for atomics + empty segments (d_out poisoned by harness).
    (void)hipMemsetAsync(out, 0, (size_t)out_size * sizeof(float), stream);

    const long long eb = (long long)CHUNK1 * CPB;     // 131072
    const int n_chunks1 = (int)(n_edges / CHUNK1);
    const size_t ws_need = (size_t)n_edges * 4 +
                           (size_t)n_chunks1 * (NREGS + 1) * 4;
    const bool v7_ok = (n_edges % eb == 0) &&
                       (n_x <= (NREGS << RSH)) &&
                       (ws_size >= ws_need);

    if (v7_ok) {
        unsigned* wse = (unsigned*)d_ws;
        int*      wsb = (int*)d_ws + n_edges;
        const int g2  = (int)(n_edges / eb);          // 256 consume blocks
        sort_chunks_kernel<<<n_chunks1, BLK1, 0, stream>>>(
            x, ptrs, csr, out, wse, wsb, eb);
        consume_kernel<<<g2, BLK2, 0, stream>>>(
            x, csr, out, wse, wsb, eb);
    } else {
        int rshift = 0;
        while ((1LL << rshift) < (n_x + NREG - 1) / NREG) ++rshift;
        const int n_chunks = (int)(((long long)n_edges + CHUNK - 1) / CHUNK);
        int grid = 1024; if (grid > n_chunks) grid = n_chunks;
        seg_gather_sort_kernel<<<grid, BLK, 0, stream>>>(
            x, ptrs, csr, out, n_edges, rshift, n_chunks);
    }
}